// Round 5
// baseline (52.283 us; speedup 1.0000x reference)
//
#include <hip/hip_runtime.h>

#define L_ 512

typedef _Float16 v8h __attribute__((ext_vector_type(8)));
typedef float    v4f __attribute__((ext_vector_type(4)));

#define MFMA(a,b,c) __builtin_amdgcn_mfma_f32_16x16x32_f16(a,b,c,0,0,0)

// grid 1024 = 256 batches x 4 query-quarters; block 256 thr = 4 waves x 32 q.
// Source dim processed in 2 chunks of 256 rows; per chunk, LDS holds the two
// round-3-VERIFIED fragment layouts (16 KB each -> 32 KB total, 4 blocks/CU):
//   wfrag [st][sr+16c][j] = wrd[st*16+sr][8c+j]          (QK A-operand, k=8g+j)
//   wtfrag[p][dt][(d&15)+16*((s>>2)&3)][(s&3)+4*((s>>4)&1)] = wrd[s][d]
//                                                        (PV A-operand, k=4g+(j&3)+16*(j>>2))
// Online softmax in log2 domain with deferred rescale (THR=14 keeps f16 P <= 2^14);
// m/l/acc carry across chunks. C/D map: col=lane&15, row=4*(lane>>4)+i (m89).
__global__ __launch_bounds__(256, 4)
void attn_refine(const float* __restrict__ rgn, const float* __restrict__ wrd,
                 const float* __restrict__ Wsc, const float* __restrict__ bsc,
                 const float* __restrict__ W1,  const float* __restrict__ b1,
                 const float* __restrict__ W2,  const float* __restrict__ b2,
                 float* __restrict__ out)
{
    __shared__ __align__(16) _Float16 wfrag[16][64][8];      // 16 KB
    __shared__ __align__(16) _Float16 wtfrag[8][2][64][8];   // 16 KB

    const int tid  = threadIdx.x;
    const int lane = tid & 63;
    const int wv   = tid >> 6;           // wave 0..3
    const int bb   = blockIdx.x & 255;   // batch
    const int qtr  = blockIdx.x >> 8;    // query quarter 0..3
    const int g    = lane >> 4;          // k-group
    const int lc   = lane & 15;          // col lane
    const int q0   = qtr * 128 + wv * 32;

    // ---- rgn B-frags (registers), slot map d = 8g+j ----
    v8h qfrag[2];
    #pragma unroll
    for (int qt = 0; qt < 2; ++qt) {
        const v4f* rr = (const v4f*)(rgn + (((size_t)bb * L_) + q0 + qt*16 + lc) * 32 + g*8);
        v4f t0 = rr[0], t1 = rr[1];
        v8h f;
        #pragma unroll
        for (int j = 0; j < 4; ++j) { f[j] = (_Float16)t0[j]; f[4+j] = (_Float16)t1[j]; }
        qfrag[qt] = f;
    }

    // ---- qm = mean(wrd row q) from global f32 (exact) ----
    float qm[2];
    #pragma unroll
    for (int qt = 0; qt < 2; ++qt) {
        const v4f* wq = (const v4f*)(wrd + ((size_t)bb * L_ + q0 + qt*16 + lc) * 32);
        float s = 0.f;
        #pragma unroll
        for (int i = 0; i < 8; ++i) {
            v4f t = wq[i];
            s += (t[0] + t[1]) + (t[2] + t[3]);
        }
        qm[qt] = s * 0.03125f;
    }

    const v4f vzero = {0.f, 0.f, 0.f, 0.f};
    const float C1 = 5.770780163555851f;   // 4*log2(e)

    float m2[2]   = {-1e30f, -1e30f};
    float nm[2]   = { 1e30f,  1e30f};      // nm = -m2
    float lsum[2] = {0.f, 0.f};
    v4f acc[2][2];
    acc[0][0] = vzero; acc[0][1] = vzero; acc[1][0] = vzero; acc[1][1] = vzero;

    for (int c0 = 0; c0 < 2; ++c0) {
        __syncthreads();
        // ---- stage chunk: thread owns wrd row s = c0*256 + tid ----
        {
            const v4f* wr4 = (const v4f*)(wrd + ((size_t)bb * L_ + c0*256 + tid) * 32);
            _Float16 wh[32];
            #pragma unroll
            for (int i = 0; i < 8; ++i) {
                v4f t = wr4[i];
                #pragma unroll
                for (int j = 0; j < 4; ++j) wh[4*i+j] = (_Float16)t[j];
            }
            const int st = tid >> 4, sr = tid & 15;
            #pragma unroll
            for (int c = 0; c < 4; ++c) {
                v8h pk;
                #pragma unroll
                for (int j = 0; j < 8; ++j) pk[j] = wh[8*c + j];
                *(v8h*)(&wfrag[st][sr + 16*c][0]) = pk;
            }
            const int pr   = tid >> 5;
            const int lgrp = 16 * ((tid >> 2) & 3);
            const int slot = (tid & 3) + 4 * ((tid >> 4) & 1);
            #pragma unroll
            for (int d = 0; d < 32; ++d)
                wtfrag[pr][d >> 4][(d & 15) + lgrp][slot] = wh[d];
        }
        __syncthreads();

        #pragma unroll 2
        for (int p = 0; p < 8; ++p) {
            v8h af0 = *(const v8h*)(&wfrag[2*p  ][lane][0]);
            v8h af1 = *(const v8h*)(&wfrag[2*p+1][lane][0]);
            v8h wt0 = *(const v8h*)(&wtfrag[p][0][lane][0]);
            v8h wt1 = *(const v8h*)(&wtfrag[p][1][lane][0]);

            v4f sa[2], sb[2];
            #pragma unroll
            for (int qt = 0; qt < 2; ++qt) {
                sa[qt] = MFMA(af0, qfrag[qt], vzero);
                sb[qt] = MFMA(af1, qfrag[qt], vzero);
            }

            // leaky in raw domain: u = max(x, 0.1x)
            float uA[2][4], uB[2][4], umax[2];
            #pragma unroll
            for (int qt = 0; qt < 2; ++qt) {
                #pragma unroll
                for (int i = 0; i < 4; ++i) {
                    float xa = sa[qt][i], xb = sb[qt][i];
                    uA[qt][i] = fmaxf(xa, 0.1f * xa);
                    uB[qt][i] = fmaxf(xb, 0.1f * xb);
                }
                float ma = fmaxf(fmaxf(uA[qt][0], uA[qt][1]), fmaxf(uA[qt][2], uA[qt][3]));
                float mb = fmaxf(fmaxf(uB[qt][0], uB[qt][1]), fmaxf(uB[qt][2], uB[qt][3]));
                umax[qt] = fmaxf(ma, mb);
            }
            int cflag = (fmaf(C1, umax[0], nm[0]) > 14.f) | (fmaf(C1, umax[1], nm[1]) > 14.f);
            if (__any(cflag)) {            // rare, wave-uniform
                #pragma unroll
                for (int qt = 0; qt < 2; ++qt) {
                    float t = C1 * umax[qt];
                    t = fmaxf(t, __shfl_xor(t, 16));
                    t = fmaxf(t, __shfl_xor(t, 32));
                    float mn = fmaxf(m2[qt], t);
                    float r  = __builtin_amdgcn_exp2f(m2[qt] - mn);   // 0 on first trigger
                    lsum[qt] *= r;
                    acc[qt][0] *= r;  acc[qt][1] *= r;
                    m2[qt] = mn;  nm[qt] = -mn;
                }
            }

            #pragma unroll
            for (int qt = 0; qt < 2; ++qt) {
                float pA[4], pB[4];
                #pragma unroll
                for (int i = 0; i < 4; ++i) {
                    pA[i] = __builtin_amdgcn_exp2f(fmaf(C1, uA[qt][i], nm[qt]));
                    pB[i] = __builtin_amdgcn_exp2f(fmaf(C1, uB[qt][i], nm[qt]));
                }
                lsum[qt] += ((pA[0]+pA[1]) + (pA[2]+pA[3])) + ((pB[0]+pB[1]) + (pB[2]+pB[3]));
                v8h pb;
                #pragma unroll
                for (int i = 0; i < 4; ++i) { pb[i] = (_Float16)pA[i]; pb[4+i] = (_Float16)pB[i]; }
                acc[qt][0] = MFMA(wt0, pb, acc[qt][0]);
                acc[qt][1] = MFMA(wt1, pb, acc[qt][1]);
            }
        }
    }

    // ---- denominators ----
    float inv[2];
    #pragma unroll
    for (int qt = 0; qt < 2; ++qt) {
        float l = lsum[qt];
        l += __shfl_xor(l, 16);
        l += __shfl_xor(l, 32);
        inv[qt] = 1.0f / l;
    }

    // ---- MLP weight/bias fragments (k-map 4g+(j&3)+16*(j>>2), matches xb) ----
    const float* Wp[3] = {Wsc, W1, W2};
    const float* bp[3] = {bsc, b1, b2};
    v8h Wf[3][2];
    v4f bv[3][2];
    #pragma unroll
    for (int ly = 0; ly < 3; ++ly) {
        #pragma unroll
        for (int jt = 0; jt < 2; ++jt) {
            const v4f ta = *(const v4f*)(Wp[ly] + (jt*16 + lc)*32 + g*4);
            const v4f tb = *(const v4f*)(Wp[ly] + (jt*16 + lc)*32 + 16 + g*4);
            v8h f;
            #pragma unroll
            for (int j = 0; j < 4; ++j) { f[j] = (_Float16)ta[j]; f[4+j] = (_Float16)tb[j]; }
            Wf[ly][jt] = f;
            bv[ly][jt] = *(const v4f*)(bp[ly] + jt*16 + g*4);
        }
    }

    const float CT = 2.885390081777927f;   // 2*log2(e)
    #pragma unroll
    for (int qt = 0; qt < 2; ++qt) {
        v8h xb;
        #pragma unroll
        for (int i = 0; i < 4; ++i) {
            xb[i]   = (_Float16)(acc[qt][0][i] * inv[qt]);
            xb[4+i] = (_Float16)(acc[qt][1][i] * inv[qt]);
        }
        v4f y0 = MFMA(Wf[0][0], xb, vzero);
        v4f y1 = MFMA(Wf[0][1], xb, vzero);
        v8h sb2;
        #pragma unroll
        for (int i = 0; i < 4; ++i) {
            float t0 = y0[i] + bv[0][0][i];
            float t1 = y1[i] + bv[0][1][i];
            float e0 = __builtin_amdgcn_exp2f(CT * t0);
            float e1 = __builtin_amdgcn_exp2f(CT * t1);
            sb2[i]   = (_Float16)(1.f - 2.f / (e0 + 1.f));   // tanh
            sb2[4+i] = (_Float16)(1.f - 2.f / (e1 + 1.f));
        }
        v4f z0 = MFMA(Wf[1][0], sb2, vzero);
        v4f z1 = MFMA(Wf[1][1], sb2, vzero);
        v8h hb;
        #pragma unroll
        for (int i = 0; i < 4; ++i) {
            hb[i]   = (_Float16)fmaxf(fmaf(qm[qt], z0[i], bv[1][0][i]), 0.f);
            hb[4+i] = (_Float16)fmaxf(fmaf(qm[qt], z1[i], bv[1][1][i]), 0.f);
        }
        v4f r0 = MFMA(Wf[2][0], hb, vzero);
        v4f r1 = MFMA(Wf[2][1], hb, vzero);
        v4f o0, o1;
        #pragma unroll
        for (int i = 0; i < 4; ++i) {
            o0[i] = r0[i] + bv[2][0][i] + qm[qt];
            o1[i] = r1[i] + bv[2][1][i] + qm[qt];
        }
        float* ob = out + ((size_t)bb * L_ + q0 + qt*16 + lc) * 32;
        *(v4f*)(ob + g*4)      = o0;
        *(v4f*)(ob + 16 + g*4) = o1;
    }
}

extern "C" void kernel_launch(void* const* d_in, const int* in_sizes, int n_in,
                              void* d_out, int out_size, void* d_ws, size_t ws_size,
                              hipStream_t stream) {
    const float* rgn = (const float*)d_in[0];
    const float* wrd = (const float*)d_in[1];
    const float* Wsc = (const float*)d_in[2];
    const float* bsc = (const float*)d_in[3];
    const float* W1  = (const float*)d_in[4];
    const float* b1  = (const float*)d_in[5];
    const float* W2  = (const float*)d_in[6];
    const float* b2  = (const float*)d_in[7];
    float* out = (float*)d_out;

    attn_refine<<<dim3(1024), dim3(256), 0, stream>>>(rgn, wrd, Wsc, bsc, W1, b1, W2, b2, out);
}

// Round 6
// 47.460 us; speedup vs baseline: 1.1016x; 1.1016x over previous
//
#include <hip/hip_runtime.h>

#define L_ 512

typedef _Float16 v8h __attribute__((ext_vector_type(8)));
typedef float    v4f __attribute__((ext_vector_type(4)));

#define MFMA(a,b,c) __builtin_amdgcn_mfma_f32_16x16x32_f16(a,b,c,0,0,0)

// grid 256 = one block per batch; block 1024 thr = 16 waves x 32 q.
// wrd staged ONCE per batch into the two round-3-verified fragment layouts
// (wfrag 32 KB + wtfrag 32 KB = 64 KB LDS):
//   wfrag [st][sr+16c][j] = wrd[st*16+sr][8c+j]            (QK A-op, k=8g+j)
//   wtfrag[p][dt][(d&15)+16*((s>>2)&3)][(s&3)+4*((s>>4)&1)] = wrd[s][d]
//                                                          (PV A-op, k=4g+(j&3)+16*(j>>2))
// Online softmax in log2 domain, deferred rescale (THR=14 keeps f16 P <= 2^14).
// C/D map: col=lane&15, row=4*(lane>>4)+i (m89-verified).
__global__ __launch_bounds__(1024)
void attn_refine(const float* __restrict__ rgn, const float* __restrict__ wrd,
                 const float* __restrict__ Wsc, const float* __restrict__ bsc,
                 const float* __restrict__ W1,  const float* __restrict__ b1,
                 const float* __restrict__ W2,  const float* __restrict__ b2,
                 float* __restrict__ out)
{
    __shared__ __align__(16) _Float16 wfrag[32][64][8];      // 32 KB
    __shared__ __align__(16) _Float16 wtfrag[16][2][64][8];  // 32 KB

    const int tid  = threadIdx.x;
    const int lane = tid & 63;
    const int wv   = tid >> 6;      // wave 0..15
    const int bb   = blockIdx.x;    // batch
    const int g    = lane >> 4;     // k-group
    const int lc   = lane & 15;     // col lane
    const int q0   = wv * 32;

    // ---- rgn B-frags (registers), slot map d = 8g+j ----
    v8h qfrag[2];
    #pragma unroll
    for (int qt = 0; qt < 2; ++qt) {
        const v4f* rr = (const v4f*)(rgn + (((size_t)bb * L_) + q0 + qt*16 + lc) * 32 + g*8);
        v4f t0 = rr[0], t1 = rr[1];
        v8h f;
        #pragma unroll
        for (int j = 0; j < 4; ++j) { f[j] = (_Float16)t0[j]; f[4+j] = (_Float16)t1[j]; }
        qfrag[qt] = f;
    }

    // ---- qm = mean(wrd row q) from global f32 (exact) ----
    float qm[2];
    #pragma unroll
    for (int qt = 0; qt < 2; ++qt) {
        const v4f* wq = (const v4f*)(wrd + ((size_t)bb * L_ + q0 + qt*16 + lc) * 32);
        float s = 0.f;
        #pragma unroll
        for (int i = 0; i < 8; ++i) {
            v4f t = wq[i];
            s += (t[0] + t[1]) + (t[2] + t[3]);
        }
        qm[qt] = s * 0.03125f;
    }

    // ---- staging (once per batch), split across thread halves ----
    {
        const int r = tid & 511;                 // source row
        const int pr   = r >> 5;
        const int lgrp = 16 * ((r >> 2) & 3);
        const int slot = (r & 3) + 4 * ((r >> 4) & 1);
        if (tid < 512) {
            const v4f* wr4 = (const v4f*)(wrd + ((size_t)bb * L_ + r) * 32);
            _Float16 wh[32];
            #pragma unroll
            for (int i = 0; i < 8; ++i) {
                v4f t = wr4[i];
                #pragma unroll
                for (int j = 0; j < 4; ++j) wh[4*i+j] = (_Float16)t[j];
            }
            const int st = r >> 4, sr = r & 15;
            #pragma unroll
            for (int c = 0; c < 4; ++c) {
                v8h pk;
                #pragma unroll
                for (int j = 0; j < 8; ++j) pk[j] = wh[8*c + j];
                *(v8h*)(&wfrag[st][sr + 16*c][0]) = pk;
            }
            #pragma unroll
            for (int d = 0; d < 16; ++d)
                wtfrag[pr][0][d + lgrp][slot] = wh[d];
        } else {
            const v4f* wr4 = (const v4f*)(wrd + ((size_t)bb * L_ + r) * 32 + 16);
            _Float16 wh[16];
            #pragma unroll
            for (int i = 0; i < 4; ++i) {
                v4f t = wr4[i];
                #pragma unroll
                for (int j = 0; j < 4; ++j) wh[4*i+j] = (_Float16)t[j];
            }
            #pragma unroll
            for (int d = 0; d < 16; ++d)
                wtfrag[pr][1][d + lgrp][slot] = wh[d];
        }
    }
    __syncthreads();

    const v4f vzero = {0.f, 0.f, 0.f, 0.f};
    const float C1 = 5.770780163555851f;   // 4*log2(e)

    float m2[2]   = {-1e30f, -1e30f};
    float nm[2]   = { 1e30f,  1e30f};      // nm = -m2
    float lsum[2] = {0.f, 0.f};
    v4f acc[2][2];
    acc[0][0] = vzero; acc[0][1] = vzero; acc[1][0] = vzero; acc[1][1] = vzero;

    #pragma unroll 2
    for (int p = 0; p < 16; ++p) {
        v8h af0 = *(const v8h*)(&wfrag[2*p  ][lane][0]);
        v8h af1 = *(const v8h*)(&wfrag[2*p+1][lane][0]);
        v8h wt0 = *(const v8h*)(&wtfrag[p][0][lane][0]);
        v8h wt1 = *(const v8h*)(&wtfrag[p][1][lane][0]);

        v4f sa[2], sb[2];
        #pragma unroll
        for (int qt = 0; qt < 2; ++qt) {
            sa[qt] = MFMA(af0, qfrag[qt], vzero);
            sb[qt] = MFMA(af1, qfrag[qt], vzero);
        }

        // leaky in raw domain: u = max(x, 0.1x)
        float uA[2][4], uB[2][4], umax[2];
        #pragma unroll
        for (int qt = 0; qt < 2; ++qt) {
            #pragma unroll
            for (int i = 0; i < 4; ++i) {
                float xa = sa[qt][i], xb = sb[qt][i];
                uA[qt][i] = fmaxf(xa, 0.1f * xa);
                uB[qt][i] = fmaxf(xb, 0.1f * xb);
            }
            float ma = fmaxf(fmaxf(uA[qt][0], uA[qt][1]), fmaxf(uA[qt][2], uA[qt][3]));
            float mb = fmaxf(fmaxf(uB[qt][0], uB[qt][1]), fmaxf(uB[qt][2], uB[qt][3]));
            umax[qt] = fmaxf(ma, mb);
        }
        int cflag = (fmaf(C1, umax[0], nm[0]) > 14.f) | (fmaf(C1, umax[1], nm[1]) > 14.f);
        if (__any(cflag)) {            // rare, wave-uniform
            #pragma unroll
            for (int qt = 0; qt < 2; ++qt) {
                float t = C1 * umax[qt];
                t = fmaxf(t, __shfl_xor(t, 16));
                t = fmaxf(t, __shfl_xor(t, 32));
                float mn = fmaxf(m2[qt], t);
                float r  = __builtin_amdgcn_exp2f(m2[qt] - mn);   // 0 on first trigger
                lsum[qt] *= r;
                acc[qt][0] *= r;  acc[qt][1] *= r;
                m2[qt] = mn;  nm[qt] = -mn;
            }
        }

        #pragma unroll
        for (int qt = 0; qt < 2; ++qt) {
            float pA[4], pB[4];
            #pragma unroll
            for (int i = 0; i < 4; ++i) {
                pA[i] = __builtin_amdgcn_exp2f(fmaf(C1, uA[qt][i], nm[qt]));
                pB[i] = __builtin_amdgcn_exp2f(fmaf(C1, uB[qt][i], nm[qt]));
            }
            lsum[qt] += ((pA[0]+pA[1]) + (pA[2]+pA[3])) + ((pB[0]+pB[1]) + (pB[2]+pB[3]));
            v8h pb;
            #pragma unroll
            for (int i = 0; i < 4; ++i) { pb[i] = (_Float16)pA[i]; pb[4+i] = (_Float16)pB[i]; }
            acc[qt][0] = MFMA(wt0, pb, acc[qt][0]);
            acc[qt][1] = MFMA(wt1, pb, acc[qt][1]);
        }
    }

    // ---- denominators ----
    float inv[2];
    #pragma unroll
    for (int qt = 0; qt < 2; ++qt) {
        float l = lsum[qt];
        l += __shfl_xor(l, 16);
        l += __shfl_xor(l, 32);
        inv[qt] = 1.0f / l;
    }

    // ---- MLP weight/bias fragments (k-map 4g+(j&3)+16*(j>>2), matches xb) ----
    const float* Wp[3] = {Wsc, W1, W2};
    const float* bp[3] = {bsc, b1, b2};
    v8h Wf[3][2];
    v4f bv[3][2];
    #pragma unroll
    for (int ly = 0; ly < 3; ++ly) {
        #pragma unroll
        for (int jt = 0; jt < 2; ++jt) {
            const v4f ta = *(const v4f*)(Wp[ly] + (jt*16 + lc)*32 + g*4);
            const v4f tb = *(const v4f*)(Wp[ly] + (jt*16 + lc)*32 + 16 + g*4);
            v8h f;
            #pragma unroll
            for (int j = 0; j < 4; ++j) { f[j] = (_Float16)ta[j]; f[4+j] = (_Float16)tb[j]; }
            Wf[ly][jt] = f;
            bv[ly][jt] = *(const v4f*)(bp[ly] + jt*16 + g*4);
        }
    }

    const float CT = 2.885390081777927f;   // 2*log2(e)
    #pragma unroll
    for (int qt = 0; qt < 2; ++qt) {
        v8h xb;
        #pragma unroll
        for (int i = 0; i < 4; ++i) {
            xb[i]   = (_Float16)(acc[qt][0][i] * inv[qt]);
            xb[4+i] = (_Float16)(acc[qt][1][i] * inv[qt]);
        }
        v4f y0 = MFMA(Wf[0][0], xb, vzero);
        v4f y1 = MFMA(Wf[0][1], xb, vzero);
        v8h sb2;
        #pragma unroll
        for (int i = 0; i < 4; ++i) {
            float t0 = y0[i] + bv[0][0][i];
            float t1 = y1[i] + bv[0][1][i];
            float e0 = __builtin_amdgcn_exp2f(CT * t0);
            float e1 = __builtin_amdgcn_exp2f(CT * t1);
            sb2[i]   = (_Float16)(1.f - 2.f / (e0 + 1.f));   // tanh
            sb2[4+i] = (_Float16)(1.f - 2.f / (e1 + 1.f));
        }
        v4f z0 = MFMA(Wf[1][0], sb2, vzero);
        v4f z1 = MFMA(Wf[1][1], sb2, vzero);
        v8h hb;
        #pragma unroll
        for (int i = 0; i < 4; ++i) {
            hb[i]   = (_Float16)fmaxf(fmaf(qm[qt], z0[i], bv[1][0][i]), 0.f);
            hb[4+i] = (_Float16)fmaxf(fmaf(qm[qt], z1[i], bv[1][1][i]), 0.f);
        }
        v4f r0 = MFMA(Wf[2][0], hb, vzero);
        v4f r1 = MFMA(Wf[2][1], hb, vzero);
        v4f o0, o1;
        #pragma unroll
        for (int i = 0; i < 4; ++i) {
            o0[i] = r0[i] + bv[2][0][i] + qm[qt];
            o1[i] = r1[i] + bv[2][1][i] + qm[qt];
        }
        float* ob = out + ((size_t)bb * L_ + q0 + qt*16 + lc) * 32;
        *(v4f*)(ob + g*4)      = o0;
        *(v4f*)(ob + 16 + g*4) = o1;
    }
}

extern "C" void kernel_launch(void* const* d_in, const int* in_sizes, int n_in,
                              void* d_out, int out_size, void* d_ws, size_t ws_size,
                              hipStream_t stream) {
    const float* rgn = (const float*)d_in[0];
    const float* wrd = (const float*)d_in[1];
    const float* Wsc = (const float*)d_in[2];
    const float* bsc = (const float*)d_in[3];
    const float* W1  = (const float*)d_in[4];
    const float* b1  = (const float*)d_in[5];
    const float* W2  = (const float*)d_in[6];
    const float* b2  = (const float*)d_in[7];
    float* out = (float*)d_out;

    attn_refine<<<dim3(256), dim3(1024), 0, stream>>>(rgn, wrd, Wsc, bsc, W1, b1, W2, b2, out);
}